// Round 2
// baseline (464.005 us; speedup 1.0000x reference)
//
#include <hip/hip_runtime.h>

// Problem constants (from reference): B=64, T=2048, D=64, V=100000
#define BB 64
#define TT 2048
#define DD 64
#define BT (BB * TT)                 // 131072
#define OFF_F 0                      // features [B,T,256]
#define OFF_T (BT * 256)             // times    [B,T]        = 33554432
#define OFF_D (OFF_T + BT)           // delta    [B,T,256]    = 33685504
#define OFF_M (OFF_D + BT * 256)     // mask     [B,T,256]    = 67239936

// Plain cached vector stores. Round-1 post-mortem: nontemporal stores bypass
// L2 write-combining -> each 16B store hits the fabric individually (~2.4 TB/s
// ceiling, both prior expand geometries pinned at the same time). Plain stores
// of full contiguous lines let L2 aggregate dirty lines and stream at ~6.4 TB/s
// (the rocclr fill demonstrates this rate on this exact buffer).
typedef float v4f __attribute__((ext_vector_type(4)));

__device__ __forceinline__ void st4(float* p, float x, float y, float z, float w) {
    v4f v = {x, y, z, w};
    *(v4f*)p = v;
}
__device__ __forceinline__ void st4v(float* p, float4 v) {
    st4(p, v.x, v.y, v.z, v.w);
}

// ---------------------------------------------------------------------------
// Phase 1: beta linear recurrence. One block = one wave per (f,b) sequence,
// 256 blocks -> 1 block/CU. Fully register-resident; no LDS, no barrier.
// beta[i] = a_i*beta[i-1] + c_i, a_i = m_{i-1}*pad_i (0/1), c_i = dt_i*pad_i.
// Output layout: beta_ws[(b*TT+i)*4 + f]  (token-major float4 per token).
// ---------------------------------------------------------------------------
__global__ __launch_bounds__(64) void beta_scan_kernel(
    const int* __restrict__ cat1, const int* __restrict__ cat2,
    const float* __restrict__ num1, const float* __restrict__ num2,
    const float* __restrict__ times, float* __restrict__ beta_ws)
{
    const int f    = blockIdx.x >> 6;
    const int b    = blockIdx.x & 63;
    const int lane = threadIdx.x;
    const int lo   = lane * 32;

    const float* trow = times + b * TT;

    float t[32], v[32];
    {
        const float4* t4 = (const float4*)(trow + lo);
        #pragma unroll
        for (int q = 0; q < 8; ++q) {
            float4 x = t4[q];
            t[4*q+0] = x.x; t[4*q+1] = x.y; t[4*q+2] = x.z; t[4*q+3] = x.w;
        }
    }
    // wave-uniform branch: f constant per block
    if (f < 2) {
        const int* crow = (f == 0 ? cat1 : cat2) + b * TT;
        const int4* c4 = (const int4*)(crow + lo);
        #pragma unroll
        for (int q = 0; q < 8; ++q) {
            int4 x = c4[q];
            v[4*q+0] = (float)x.x; v[4*q+1] = (float)x.y;
            v[4*q+2] = (float)x.z; v[4*q+3] = (float)x.w;
        }
    } else {
        const float* nrow = (f == 2 ? num1 : num2) + b * TT;
        const float4* n4 = (const float4*)(nrow + lo);
        #pragma unroll
        for (int q = 0; q < 8; ++q) {
            float4 x = n4[q];
            v[4*q+0] = x.x; v[4*q+1] = x.y; v[4*q+2] = x.z; v[4*q+3] = x.w;
        }
    }
    // boundary values for k==0 (lane>0 reads element lo-1)
    float tprev = 0.f, vprev = 0.f;
    if (lane > 0) {
        tprev = trow[lo - 1];
        if      (f == 0) vprev = (float)cat1[b * TT + lo - 1];
        else if (f == 1) vprev = (float)cat2[b * TT + lo - 1];
        else if (f == 2) vprev = num1[b * TT + lo - 1];
        else             vprev = num2[b * TT + lo - 1];
    }

    // pass 1: compose this lane's 32 affine steps
    float A = 1.f, C = 0.f;
    #pragma unroll
    for (int k = 0; k < 32; ++k) {
        float a, c;
        if (lo + k == 0) { a = 0.f; c = 0.f; }          // beta[0] = 0
        else {
            float ti  = t[k];
            float tp  = (k == 0) ? tprev : t[k-1];
            float fv  = (k == 0) ? vprev : v[k-1];
            float pad = (ti != -1.f) ? 1.f : 0.f;
            float m   = (fv != -1.f && fv != 0.f) ? 1.f : 0.f;
            a = m * pad;
            c = (ti - tp) * pad;
        }
        C = a * C + c;
        A = A * a;
    }
    // inclusive wave scan (affine composition)
    for (int d = 1; d < 64; d <<= 1) {
        float Ap = __shfl_up(A, d);
        float Cp = __shfl_up(C, d);
        if (lane >= d) { C = A * Cp + C; A = A * Ap; }
    }
    float beta = __shfl_up(C, 1);
    if (lane == 0) beta = 0.f;

    // pass 2: replay with true incoming beta, write token-major [bt][f]
    float* out = beta_ws + (size_t)b * TT * 4 + f;
    #pragma unroll
    for (int k = 0; k < 32; ++k) {
        float a, c;
        if (lo + k == 0) { a = 0.f; c = 0.f; }
        else {
            float ti  = t[k];
            float tp  = (k == 0) ? tprev : t[k-1];
            float fv  = (k == 0) ? vprev : v[k-1];
            float pad = (ti != -1.f) ? 1.f : 0.f;
            float m   = (fv != -1.f && fv != 0.f) ? 1.f : 0.f;
            a = m * pad;
            c = (ti - tp) * pad;
        }
        beta = a * beta + c;
        out[(lo + k) * 4] = beta;
    }
}

// ---------------------------------------------------------------------------
// Phase 2: expansion, ONE WAVE = ONE TOKEN.
//   lane = one float4 chunk of the 256-float output row
//   q = lane>>4 selects the feature quarter {E1-row, E2-row, num1-fma, num2-fma}
// bt is wave-uniform -> cat/num/beta reads scalarize; each wave issues exactly
// 3 stores, each a CONTIGUOUS 1KB line (features / delta / mask), now PLAIN
// cached stores (full dirty lines -> L2 write-combining at fill-kernel rate).
// ---------------------------------------------------------------------------
__global__ __launch_bounds__(256) void expand_kernel(
    const int* __restrict__ cat1, const int* __restrict__ cat2,
    const float* __restrict__ num1, const float* __restrict__ num2,
    const float* __restrict__ times,
    const float* __restrict__ E1, const float* __restrict__ E2,
    const float* __restrict__ w1, const float* __restrict__ b1,
    const float* __restrict__ w2, const float* __restrict__ b2,
    const float* __restrict__ beta_ws, float* __restrict__ out)
{
    const int u    = blockIdx.x * 256 + threadIdx.x;   // [0, BT*64)
    const int lane = threadIdx.x & 63;
    const int wid  = __builtin_amdgcn_readfirstlane((int)(threadIdx.x >> 6));
    const int bt   = (blockIdx.x << 2) | wid;          // wave-uniform token id
    const int q    = lane >> 4;                        // feature quarter 0..3
    const int c    = lane & 15;                        // float4 chunk in [0,16)

    const int   i1 = cat1[bt];
    const int   i2 = cat2[bt];
    const float x1 = num1[bt];
    const float x2 = num2[bt];
    const float4 bet = ((const float4*)beta_ws)[bt];   // (f0,f1,f2,f3)

    // per-lane source pointer for the "a" operand of this quarter
    const float* srcA = (q == 0) ? E1 + (size_t)i1 * DD
                      : (q == 1) ? E2 + (size_t)i2 * DD
                      : (q == 2) ? w1 : w2;
    const float* srcB = (q == 3) ? b2 : b1;            // harmless dummy for q<2
    const float  x    = (q == 3) ? x2 : x1;

    const float4 a  = ((const float4*)srcA)[c];
    const float4 bb = ((const float4*)srcB)[c];

    float4 nv = make_float4(fmaf(x, a.x, bb.x), fmaf(x, a.y, bb.y),
                            fmaf(x, a.z, bb.z), fmaf(x, a.w, bb.w));
    float4 val;
    val.x = (q < 2) ? a.x : nv.x;
    val.y = (q < 2) ? a.y : nv.y;
    val.z = (q < 2) ? a.z : nv.z;
    val.w = (q < 2) ? a.w : nv.w;

    // per-quarter mask / beta scalar (wave-uniform operands, lane select)
    const float m1 = (i1 != -1   && i1 != 0  ) ? 1.f : 0.f;
    const float m2 = (i2 != -1   && i2 != 0  ) ? 1.f : 0.f;
    const float m3 = (x1 != -1.f && x1 != 0.f) ? 1.f : 0.f;
    const float m4 = (x2 != -1.f && x2 != 0.f) ? 1.f : 0.f;
    const float m  = (q == 0) ? m1 : (q == 1) ? m2 : (q == 2) ? m3 : m4;
    const float bv = (q == 0) ? bet.x : (q == 1) ? bet.y : (q == 2) ? bet.z : bet.w;

    const size_t o = ((size_t)bt << 6) | (size_t)lane; // float4 index in region
    st4v(out + OFF_F + (o << 2), val);
    st4 (out + OFF_D + (o << 2), bv, bv, bv, bv);
    st4 (out + OFF_M + (o << 2), m, m, m, m);

    // times copy: first BT/4 threads, coalesced float4
    if (u < BT / 4) {
        float4 t = ((const float4*)times)[u];
        st4v(out + OFF_T + 4 * u, t);
    }
}

extern "C" void kernel_launch(void* const* d_in, const int* in_sizes, int n_in,
                              void* d_out, int out_size, void* d_ws, size_t ws_size,
                              hipStream_t stream) {
    const int*   cat1  = (const int*)d_in[0];
    const int*   cat2  = (const int*)d_in[1];
    const float* num1  = (const float*)d_in[2];
    const float* num2  = (const float*)d_in[3];
    const float* times = (const float*)d_in[4];
    const float* E1    = (const float*)d_in[5];
    const float* E2    = (const float*)d_in[6];
    const float* w1    = (const float*)d_in[7];
    const float* b1    = (const float*)d_in[8];
    const float* w2    = (const float*)d_in[9];
    const float* b2    = (const float*)d_in[10];
    float* out     = (float*)d_out;
    float* beta_ws = (float*)d_ws;   // 4*B*T*4 = 2 MB scratch, [bt][f] layout

    beta_scan_kernel<<<4 * BB, 64, 0, stream>>>(cat1, cat2, num1, num2, times, beta_ws);

    expand_kernel<<<(BT * 64) / 256, 256, 0, stream>>>(
        cat1, cat2, num1, num2, times, E1, E2, w1, b1, w2, b2, beta_ws, out);
}

// Round 4
// 457.985 us; speedup vs baseline: 1.0131x; 1.0131x over previous
//
#include <hip/hip_runtime.h>

// Problem constants (from reference): B=64, T=2048, D=64, V=100000
#define BB 64
#define TT 2048
#define DD 64
#define BT (BB * TT)                 // 131072
#define OFF_F 0                      // features [B,T,256]
#define OFF_T (BT * 256)             // times    [B,T]        = 33554432
#define OFF_D (OFF_T + BT)           // delta    [B,T,256]    = 33685504
#define OFF_M (OFF_D + BT * 256)     // mask     [B,T,256]    = 67239936

// native 4-float vector for nontemporal builtins (float4 is a class -> rejected)
typedef float v4f __attribute__((ext_vector_type(4)));

__device__ __forceinline__ void nt_store4(float* p, float x, float y, float z, float w) {
    v4f v = {x, y, z, w};
    __builtin_nontemporal_store(v, (v4f*)p);
}
__device__ __forceinline__ void nt_store4v(float* p, float4 v) {
    nt_store4(p, v.x, v.y, v.z, v.w);
}

// ---------------------------------------------------------------------------
// Phase 1: beta linear recurrence. One block = one wave per (f,b) sequence,
// 256 blocks -> 1 block/CU. Fully register-resident; no LDS, no barrier.
// beta[i] = a_i*beta[i-1] + c_i, a_i = m_{i-1}*pad_i (0/1), c_i = dt_i*pad_i.
// Output layout: beta_ws[(b*TT+i)*4 + f]  (token-major float4 per token).
// ---------------------------------------------------------------------------
__global__ __launch_bounds__(64) void beta_scan_kernel(
    const int* __restrict__ cat1, const int* __restrict__ cat2,
    const float* __restrict__ num1, const float* __restrict__ num2,
    const float* __restrict__ times, float* __restrict__ beta_ws)
{
    const int f    = blockIdx.x >> 6;
    const int b    = blockIdx.x & 63;
    const int lane = threadIdx.x;
    const int lo   = lane * 32;

    const float* trow = times + b * TT;

    float t[32], v[32];
    {
        const float4* t4 = (const float4*)(trow + lo);
        #pragma unroll
        for (int q = 0; q < 8; ++q) {
            float4 x = t4[q];
            t[4*q+0] = x.x; t[4*q+1] = x.y; t[4*q+2] = x.z; t[4*q+3] = x.w;
        }
    }
    // wave-uniform branch: f constant per block
    if (f < 2) {
        const int* crow = (f == 0 ? cat1 : cat2) + b * TT;
        const int4* c4 = (const int4*)(crow + lo);
        #pragma unroll
        for (int q = 0; q < 8; ++q) {
            int4 x = c4[q];
            v[4*q+0] = (float)x.x; v[4*q+1] = (float)x.y;
            v[4*q+2] = (float)x.z; v[4*q+3] = (float)x.w;
        }
    } else {
        const float* nrow = (f == 2 ? num1 : num2) + b * TT;
        const float4* n4 = (const float4*)(nrow + lo);
        #pragma unroll
        for (int q = 0; q < 8; ++q) {
            float4 x = n4[q];
            v[4*q+0] = x.x; v[4*q+1] = x.y; v[4*q+2] = x.z; v[4*q+3] = x.w;
        }
    }
    // boundary values for k==0 (lane>0 reads element lo-1)
    float tprev = 0.f, vprev = 0.f;
    if (lane > 0) {
        tprev = trow[lo - 1];
        if      (f == 0) vprev = (float)cat1[b * TT + lo - 1];
        else if (f == 1) vprev = (float)cat2[b * TT + lo - 1];
        else if (f == 2) vprev = num1[b * TT + lo - 1];
        else             vprev = num2[b * TT + lo - 1];
    }

    // pass 1: compose this lane's 32 affine steps
    float A = 1.f, C = 0.f;
    #pragma unroll
    for (int k = 0; k < 32; ++k) {
        float a, c;
        if (lo + k == 0) { a = 0.f; c = 0.f; }          // beta[0] = 0
        else {
            float ti  = t[k];
            float tp  = (k == 0) ? tprev : t[k-1];
            float fv  = (k == 0) ? vprev : v[k-1];
            float pad = (ti != -1.f) ? 1.f : 0.f;
            float m   = (fv != -1.f && fv != 0.f) ? 1.f : 0.f;
            a = m * pad;
            c = (ti - tp) * pad;
        }
        C = a * C + c;
        A = A * a;
    }
    // inclusive wave scan (affine composition)
    for (int d = 1; d < 64; d <<= 1) {
        float Ap = __shfl_up(A, d);
        float Cp = __shfl_up(C, d);
        if (lane >= d) { C = A * Cp + C; A = A * Ap; }
    }
    float beta = __shfl_up(C, 1);
    if (lane == 0) beta = 0.f;

    // pass 2: replay with true incoming beta, write token-major [bt][f]
    float* out = beta_ws + (size_t)b * TT * 4 + f;
    #pragma unroll
    for (int k = 0; k < 32; ++k) {
        float a, c;
        if (lo + k == 0) { a = 0.f; c = 0.f; }
        else {
            float ti  = t[k];
            float tp  = (k == 0) ? tprev : t[k-1];
            float fv  = (k == 0) ? vprev : v[k-1];
            float pad = (ti != -1.f) ? 1.f : 0.f;
            float m   = (fv != -1.f && fv != 0.f) ? 1.f : 0.f;
            a = m * pad;
            c = (ti - tp) * pad;
        }
        beta = a * beta + c;
        out[(lo + k) * 4] = beta;
    }
}

// ---------------------------------------------------------------------------
// Phase 2: expansion, ONE WAVE = FOUR TOKENS (4x memory-level parallelism per
// wave). Both earlier geometries (thread-per-chunk, wave-per-token) pinned at
// the same duration -> shared limiter hypothesized as the one-token-deep
// dependent chain  idx-load -> E-row gather -> store  per wave. Now:
//   - all 4 tokens' indices/nums/betas batch into wave-uniform s_loads
//   - all 4 (per-lane) E-row gathers issue back-to-back (4 chains in flight)
//   - then 12 independent contiguous-1KB NT stores
// lane = one float4 chunk of the 256-float output row; q = lane>>4 selects
// the feature quarter {E1-row, E2-row, num1-fma, num2-fma}; c = chunk in row.
// ---------------------------------------------------------------------------
__global__ __launch_bounds__(256) void expand_kernel(
    const int* __restrict__ cat1, const int* __restrict__ cat2,
    const float* __restrict__ num1, const float* __restrict__ num2,
    const float* __restrict__ times,
    const float* __restrict__ E1, const float* __restrict__ E2,
    const float* __restrict__ w1, const float* __restrict__ b1,
    const float* __restrict__ w2, const float* __restrict__ b2,
    const float* __restrict__ beta_ws, float* __restrict__ out)
{
    const int u    = blockIdx.x * 256 + threadIdx.x;
    const int lane = threadIdx.x & 63;
    const int wid  = __builtin_amdgcn_readfirstlane((int)(threadIdx.x >> 6));
    const int bt0  = (blockIdx.x << 4) | (wid << 2);   // 16 tokens/block, 4/wave
    const int q    = lane >> 4;                        // feature quarter 0..3
    const int c    = lane & 15;                        // float4 chunk in [0,16)

    // batched wave-uniform loads: 4 tokens of indices / nums / betas
    const int4   i1v = *(const int4*)(cat1 + bt0);
    const int4   i2v = *(const int4*)(cat2 + bt0);
    const float4 x1v = *(const float4*)(num1 + bt0);
    const float4 x2v = *(const float4*)(num2 + bt0);
    const float4 be0 = ((const float4*)beta_ws)[bt0 + 0];
    const float4 be1 = ((const float4*)beta_ws)[bt0 + 1];
    const float4 be2 = ((const float4*)beta_ws)[bt0 + 2];
    const float4 be3 = ((const float4*)beta_ws)[bt0 + 3];

    // per-lane source pointers for the "a" operand, all 4 tokens
    const float* s0 = (q == 0) ? E1 + (size_t)i1v.x * DD
                   : (q == 1) ? E2 + (size_t)i2v.x * DD
                   : (q == 2) ? w1 : w2;
    const float* s1 = (q == 0) ? E1 + (size_t)i1v.y * DD
                   : (q == 1) ? E2 + (size_t)i2v.y * DD
                   : (q == 2) ? w1 : w2;
    const float* s2 = (q == 0) ? E1 + (size_t)i1v.z * DD
                   : (q == 1) ? E2 + (size_t)i2v.z * DD
                   : (q == 2) ? w1 : w2;
    const float* s3 = (q == 0) ? E1 + (size_t)i1v.w * DD
                   : (q == 1) ? E2 + (size_t)i2v.w * DD
                   : (q == 2) ? w1 : w2;

    // issue all 4 row gathers back-to-back (independent, 4x MLP)
    const float4 a0 = ((const float4*)s0)[c];
    const float4 a1 = ((const float4*)s1)[c];
    const float4 a2 = ((const float4*)s2)[c];
    const float4 a3 = ((const float4*)s3)[c];
    // bias chunk (token-independent; L1-resident)
    const float4 bb = ((const float4*)((q == 3) ? b2 : b1))[c];

#define EMIT_TOKEN(J, AJ, BEJ, I1, I2, X1, X2)                                  \
    {                                                                           \
        const float x  = (q == 3) ? (X2) : (X1);                                \
        float4 val;                                                             \
        val.x = (q < 2) ? (AJ).x : fmaf(x, (AJ).x, bb.x);                       \
        val.y = (q < 2) ? (AJ).y : fmaf(x, (AJ).y, bb.y);                       \
        val.z = (q < 2) ? (AJ).z : fmaf(x, (AJ).z, bb.z);                       \
        val.w = (q < 2) ? (AJ).w : fmaf(x, (AJ).w, bb.w);                       \
        const float m1 = ((I1) != -1   && (I1) != 0  ) ? 1.f : 0.f;             \
        const float m2 = ((I2) != -1   && (I2) != 0  ) ? 1.f : 0.f;             \
        const float m3 = ((X1) != -1.f && (X1) != 0.f) ? 1.f : 0.f;             \
        const float m4 = ((X2) != -1.f && (X2) != 0.f) ? 1.f : 0.f;             \
        const float m  = (q == 0) ? m1 : (q == 1) ? m2 : (q == 2) ? m3 : m4;    \
        const float bv = (q == 0) ? (BEJ).x : (q == 1) ? (BEJ).y                \
                       : (q == 2) ? (BEJ).z : (BEJ).w;                          \
        const size_t o = ((size_t)(bt0 + (J)) << 6) | (size_t)lane;             \
        nt_store4v(out + OFF_F + (o << 2), val);                                \
        nt_store4 (out + OFF_D + (o << 2), bv, bv, bv, bv);                     \
        nt_store4 (out + OFF_M + (o << 2), m, m, m, m);                         \
    }

    EMIT_TOKEN(0, a0, be0, i1v.x, i2v.x, x1v.x, x2v.x)
    EMIT_TOKEN(1, a1, be1, i1v.y, i2v.y, x1v.y, x2v.y)
    EMIT_TOKEN(2, a2, be2, i1v.z, i2v.z, x1v.z, x2v.z)
    EMIT_TOKEN(3, a3, be3, i1v.w, i2v.w, x1v.w, x2v.w)
#undef EMIT_TOKEN

    // times copy: first BT/4 threads, coalesced float4
    if (u < BT / 4) {
        float4 t = ((const float4*)times)[u];
        nt_store4v(out + OFF_T + 4 * u, t);
    }
}

extern "C" void kernel_launch(void* const* d_in, const int* in_sizes, int n_in,
                              void* d_out, int out_size, void* d_ws, size_t ws_size,
                              hipStream_t stream) {
    const int*   cat1  = (const int*)d_in[0];
    const int*   cat2  = (const int*)d_in[1];
    const float* num1  = (const float*)d_in[2];
    const float* num2  = (const float*)d_in[3];
    const float* times = (const float*)d_in[4];
    const float* E1    = (const float*)d_in[5];
    const float* E2    = (const float*)d_in[6];
    const float* w1    = (const float*)d_in[7];
    const float* b1    = (const float*)d_in[8];
    const float* w2    = (const float*)d_in[9];
    const float* b2    = (const float*)d_in[10];
    float* out     = (float*)d_out;
    float* beta_ws = (float*)d_ws;   // 4*B*T*4 = 2 MB scratch, [bt][f] layout

    beta_scan_kernel<<<4 * BB, 64, 0, stream>>>(cat1, cat2, num1, num2, times, beta_ws);

    // 16 tokens per 256-thread block
    expand_kernel<<<BT / 16, 256, 0, stream>>>(
        cat1, cat2, num1, num2, times, E1, E2, w1, b1, w2, b2, beta_ws, out);
}

// Round 5
// 450.859 us; speedup vs baseline: 1.0292x; 1.0158x over previous
//
#include <hip/hip_runtime.h>

// Problem constants (from reference): B=64, T=2048, D=64, V=100000
#define BB 64
#define TT 2048
#define DD 64
#define BT (BB * TT)                 // 131072
#define OFF_F 0                      // features [B,T,256]
#define OFF_T (BT * 256)             // times    [B,T]        = 33554432
#define OFF_D (OFF_T + BT)           // delta    [B,T,256]    = 33685504
#define OFF_M (OFF_D + BT * 256)     // mask     [B,T,256]    = 67239936

// native 4-float vector for nontemporal builtins (float4 is a class -> rejected)
typedef float v4f __attribute__((ext_vector_type(4)));

__device__ __forceinline__ void nt_store4(float* p, float x, float y, float z, float w) {
    v4f v = {x, y, z, w};
    __builtin_nontemporal_store(v, (v4f*)p);
}
__device__ __forceinline__ void nt_store4v(float* p, float4 v) {
    nt_store4(p, v.x, v.y, v.z, v.w);
}

// ---------------------------------------------------------------------------
// Phase 1: beta linear recurrence. One block = one wave per (f,b) sequence,
// 256 blocks -> 1 block/CU. Fully register-resident; no LDS, no barrier.
// beta[i] = a_i*beta[i-1] + c_i, a_i = m_{i-1}*pad_i (0/1), c_i = dt_i*pad_i.
// Output layout: beta_ws[(b*TT+i)*4 + f]  (token-major float4 per token).
// ---------------------------------------------------------------------------
__global__ __launch_bounds__(64) void beta_scan_kernel(
    const int* __restrict__ cat1, const int* __restrict__ cat2,
    const float* __restrict__ num1, const float* __restrict__ num2,
    const float* __restrict__ times, float* __restrict__ beta_ws)
{
    const int f    = blockIdx.x >> 6;
    const int b    = blockIdx.x & 63;
    const int lane = threadIdx.x;
    const int lo   = lane * 32;

    const float* trow = times + b * TT;

    float t[32], v[32];
    {
        const float4* t4 = (const float4*)(trow + lo);
        #pragma unroll
        for (int q = 0; q < 8; ++q) {
            float4 x = t4[q];
            t[4*q+0] = x.x; t[4*q+1] = x.y; t[4*q+2] = x.z; t[4*q+3] = x.w;
        }
    }
    // wave-uniform branch: f constant per block
    if (f < 2) {
        const int* crow = (f == 0 ? cat1 : cat2) + b * TT;
        const int4* c4 = (const int4*)(crow + lo);
        #pragma unroll
        for (int q = 0; q < 8; ++q) {
            int4 x = c4[q];
            v[4*q+0] = (float)x.x; v[4*q+1] = (float)x.y;
            v[4*q+2] = (float)x.z; v[4*q+3] = (float)x.w;
        }
    } else {
        const float* nrow = (f == 2 ? num1 : num2) + b * TT;
        const float4* n4 = (const float4*)(nrow + lo);
        #pragma unroll
        for (int q = 0; q < 8; ++q) {
            float4 x = n4[q];
            v[4*q+0] = x.x; v[4*q+1] = x.y; v[4*q+2] = x.z; v[4*q+3] = x.w;
        }
    }
    // boundary values for k==0 (lane>0 reads element lo-1)
    float tprev = 0.f, vprev = 0.f;
    if (lane > 0) {
        tprev = trow[lo - 1];
        if      (f == 0) vprev = (float)cat1[b * TT + lo - 1];
        else if (f == 1) vprev = (float)cat2[b * TT + lo - 1];
        else if (f == 2) vprev = num1[b * TT + lo - 1];
        else             vprev = num2[b * TT + lo - 1];
    }

    // pass 1: compose this lane's 32 affine steps
    float A = 1.f, C = 0.f;
    #pragma unroll
    for (int k = 0; k < 32; ++k) {
        float a, c;
        if (lo + k == 0) { a = 0.f; c = 0.f; }          // beta[0] = 0
        else {
            float ti  = t[k];
            float tp  = (k == 0) ? tprev : t[k-1];
            float fv  = (k == 0) ? vprev : v[k-1];
            float pad = (ti != -1.f) ? 1.f : 0.f;
            float m   = (fv != -1.f && fv != 0.f) ? 1.f : 0.f;
            a = m * pad;
            c = (ti - tp) * pad;
        }
        C = a * C + c;
        A = A * a;
    }
    // inclusive wave scan (affine composition)
    for (int d = 1; d < 64; d <<= 1) {
        float Ap = __shfl_up(A, d);
        float Cp = __shfl_up(C, d);
        if (lane >= d) { C = A * Cp + C; A = A * Ap; }
    }
    float beta = __shfl_up(C, 1);
    if (lane == 0) beta = 0.f;

    // pass 2: replay with true incoming beta, write token-major [bt][f]
    float* out = beta_ws + (size_t)b * TT * 4 + f;
    #pragma unroll
    for (int k = 0; k < 32; ++k) {
        float a, c;
        if (lo + k == 0) { a = 0.f; c = 0.f; }
        else {
            float ti  = t[k];
            float tp  = (k == 0) ? tprev : t[k-1];
            float fv  = (k == 0) ? vprev : v[k-1];
            float pad = (ti != -1.f) ? 1.f : 0.f;
            float m   = (fv != -1.f && fv != 0.f) ? 1.f : 0.f;
            a = m * pad;
            c = (ti - tp) * pad;
        }
        beta = a * beta + c;
        out[(lo + k) * 4] = beta;
    }
}

// ---------------------------------------------------------------------------
// Phase 2a: FEATURES region only (+ times copy). One wave = 4 tokens, same
// gather structure as r4 but writes a SINGLE output stream. lane: q = quarter
// {E1,E2,num1-fma,num2-fma}, c = float4 chunk within the 64-float quarter.
// ---------------------------------------------------------------------------
__global__ __launch_bounds__(256) void feat_kernel(
    const int* __restrict__ cat1, const int* __restrict__ cat2,
    const float* __restrict__ num1, const float* __restrict__ num2,
    const float* __restrict__ times,
    const float* __restrict__ E1, const float* __restrict__ E2,
    const float* __restrict__ w1, const float* __restrict__ b1,
    const float* __restrict__ w2, const float* __restrict__ b2,
    float* __restrict__ out)
{
    const int u    = blockIdx.x * 256 + threadIdx.x;
    const int lane = threadIdx.x & 63;
    const int wid  = __builtin_amdgcn_readfirstlane((int)(threadIdx.x >> 6));
    const int bt0  = (blockIdx.x << 4) | (wid << 2);   // 16 tokens/block, 4/wave
    const int q    = lane >> 4;                        // feature quarter 0..3
    const int c    = lane & 15;                        // float4 chunk in [0,16)

    const int4   i1v = *(const int4*)(cat1 + bt0);
    const int4   i2v = *(const int4*)(cat2 + bt0);
    const float4 x1v = *(const float4*)(num1 + bt0);
    const float4 x2v = *(const float4*)(num2 + bt0);

    const float* s0 = (q == 0) ? E1 + (size_t)i1v.x * DD
                   : (q == 1) ? E2 + (size_t)i2v.x * DD
                   : (q == 2) ? w1 : w2;
    const float* s1 = (q == 0) ? E1 + (size_t)i1v.y * DD
                   : (q == 1) ? E2 + (size_t)i2v.y * DD
                   : (q == 2) ? w1 : w2;
    const float* s2 = (q == 0) ? E1 + (size_t)i1v.z * DD
                   : (q == 1) ? E2 + (size_t)i2v.z * DD
                   : (q == 2) ? w1 : w2;
    const float* s3 = (q == 0) ? E1 + (size_t)i1v.w * DD
                   : (q == 1) ? E2 + (size_t)i2v.w * DD
                   : (q == 2) ? w1 : w2;

    const float4 a0 = ((const float4*)s0)[c];
    const float4 a1 = ((const float4*)s1)[c];
    const float4 a2 = ((const float4*)s2)[c];
    const float4 a3 = ((const float4*)s3)[c];
    const float4 bb = ((const float4*)((q == 3) ? b2 : b1))[c];

#define EMIT_F(J, AJ, X1, X2)                                                   \
    {                                                                           \
        const float x  = (q == 3) ? (X2) : (X1);                                \
        float4 val;                                                             \
        val.x = (q < 2) ? (AJ).x : fmaf(x, (AJ).x, bb.x);                       \
        val.y = (q < 2) ? (AJ).y : fmaf(x, (AJ).y, bb.y);                       \
        val.z = (q < 2) ? (AJ).z : fmaf(x, (AJ).z, bb.z);                       \
        val.w = (q < 2) ? (AJ).w : fmaf(x, (AJ).w, bb.w);                       \
        const size_t o = ((size_t)(bt0 + (J)) << 6) | (size_t)lane;             \
        nt_store4v(out + OFF_F + (o << 2), val);                                \
    }

    EMIT_F(0, a0, x1v.x, x2v.x)
    EMIT_F(1, a1, x1v.y, x2v.y)
    EMIT_F(2, a2, x1v.z, x2v.z)
    EMIT_F(3, a3, x1v.w, x2v.w)
#undef EMIT_F

    // times copy: first BT/4 threads, coalesced float4
    if (u < BT / 4) {
        float4 t = ((const float4*)times)[u];
        nt_store4v(out + OFF_T + 4 * u, t);
    }
}

// ---------------------------------------------------------------------------
// Phase 2b: DELTA region — pure computed fill, single global write stream.
// One float4 store per thread, 1KB/instr contiguous per wave (fill-identical
// store pattern). Scalar beta read shared by 16 consecutive threads (L2-hit).
// ---------------------------------------------------------------------------
__global__ __launch_bounds__(256) void delta_kernel(
    const float* __restrict__ beta_ws, float* __restrict__ out)
{
    const int g     = blockIdx.x * 256 + threadIdx.x;  // float4 idx in region
    const int token = g >> 6;
    const int f     = (g >> 4) & 3;
    const float bv  = beta_ws[token * 4 + f];
    nt_store4(out + OFF_D + ((size_t)g << 2), bv, bv, bv, bv);
}

// ---------------------------------------------------------------------------
// Phase 2c: MASK region — pure computed fill, single global write stream.
// ---------------------------------------------------------------------------
__global__ __launch_bounds__(256) void mask_kernel(
    const int* __restrict__ cat1, const int* __restrict__ cat2,
    const float* __restrict__ num1, const float* __restrict__ num2,
    float* __restrict__ out)
{
    const int g     = blockIdx.x * 256 + threadIdx.x;  // float4 idx in region
    const int token = g >> 6;
    const int f     = (g >> 4) & 3;
    float m;
    if (f < 2) {
        const int i = (f == 0) ? cat1[token] : cat2[token];
        m = (i != -1 && i != 0) ? 1.f : 0.f;
    } else {
        const float x = (f == 2) ? num1[token] : num2[token];
        m = (x != -1.f && x != 0.f) ? 1.f : 0.f;
    }
    nt_store4(out + OFF_M + ((size_t)g << 2), m, m, m, m);
}

extern "C" void kernel_launch(void* const* d_in, const int* in_sizes, int n_in,
                              void* d_out, int out_size, void* d_ws, size_t ws_size,
                              hipStream_t stream) {
    const int*   cat1  = (const int*)d_in[0];
    const int*   cat2  = (const int*)d_in[1];
    const float* num1  = (const float*)d_in[2];
    const float* num2  = (const float*)d_in[3];
    const float* times = (const float*)d_in[4];
    const float* E1    = (const float*)d_in[5];
    const float* E2    = (const float*)d_in[6];
    const float* w1    = (const float*)d_in[7];
    const float* b1    = (const float*)d_in[8];
    const float* w2    = (const float*)d_in[9];
    const float* b2    = (const float*)d_in[10];
    float* out     = (float*)d_out;
    float* beta_ws = (float*)d_ws;   // 4*B*T*4 = 2 MB scratch, [bt][f] layout

    beta_scan_kernel<<<4 * BB, 64, 0, stream>>>(cat1, cat2, num1, num2, times, beta_ws);

    // region-pure sequential streams: F (+times), then D, then M
    feat_kernel<<<BT / 16, 256, 0, stream>>>(
        cat1, cat2, num1, num2, times, E1, E2, w1, b1, w2, b2, out);
    delta_kernel<<<(BT * 64) / 256, 256, 0, stream>>>(beta_ws, out);
    mask_kernel<<<(BT * 64) / 256, 256, 0, stream>>>(cat1, cat2, num1, num2, out);
}